// Round 1
// baseline (349.759 us; speedup 1.0000x reference)
//
#include <hip/hip_runtime.h>
#include <hip/hip_bf16.h>

#define N_SUP 32768
#define M_Q 32768
#define H_NB 32
#define K_PTS 15
#define CIN 64
#define COUT 64
#define SIGMA_ 0.1f
#define NGROUPS 8
#define NEG_SLOPE_ 0.1f
#define GEPS 1e-5f

#define QPB 16   // queries per block
#define NWAVES 4

__device__ __forceinline__ float bfu_to_f(unsigned int lo16) {
    unsigned int x = lo16 << 16;
    return __builtin_bit_cast(float, x);
}
__device__ __forceinline__ unsigned short f_to_bf16(float f) {
    unsigned int x = __builtin_bit_cast(unsigned int, f);
    unsigned int r = (x + 0x7fffu + ((x >> 16) & 1u)) >> 16;
    return (unsigned short)r;
}

__global__ __launch_bounds__(256) void kpconv_kernel(
    const float* __restrict__ s_feats,
    const float* __restrict__ q_points,
    const float* __restrict__ s_points,
    const int*   __restrict__ nbr_idx,
    const float* __restrict__ kpts,
    const float* __restrict__ weights,
    const float* __restrict__ bias,
    float* __restrict__ y_out,      // d_out: pre-GN conv output [M, COUT]
    float* __restrict__ gstats)     // ws: 16 floats (sum[8], sumsq[8])
{
    __shared__ float w_lds[NWAVES][H_NB][16];            // 8 KB
    __shared__ unsigned short wtd_lds[QPB][K_PTS][CIN];  // 30 KB (bf16)
    __shared__ float y_red[QPB][COUT];                   // 4 KB
    __shared__ float nbr_lds[QPB];

    const int tid  = threadIdx.x;
    const int lane = tid & 63;
    const int wid  = __builtin_amdgcn_readfirstlane(tid >> 6);

    // zero the block-level reduction buffer
    for (int i = tid; i < QPB * COUT; i += 256) ((float*)y_red)[i] = 0.f;

    // kernel points (uniform across all threads -> scalar regs)
    float kpx[K_PTS], kpy[K_PTS], kpz[K_PTS];
#pragma unroll
    for (int k = 0; k < K_PTS; ++k) {
        kpx[k] = kpts[k * 3 + 0];
        kpy[k] = kpts[k * 3 + 1];
        kpz[k] = kpts[k * 3 + 2];
    }
    __syncthreads();

    const int h1    = lane >> 1;   // phase-1: 2 lanes per neighbor
    const int khalf = lane & 1;    // each lane does 8 kernel points

    for (int i = 0; i < QPB / NWAVES; ++i) {
        const int q = wid * (QPB / NWAVES) + i;   // query slot in block
        const int m = blockIdx.x * QPB + q;       // global query id

        // ---------------- phase 1: w[h][k], lane-parallel ----------------
        const float qx = q_points[m * 3 + 0];
        const float qy = q_points[m * 3 + 1];
        const float qz = q_points[m * 3 + 2];
        const int idx1 = nbr_idx[m * H_NB + h1];
        const float dx = s_points[idx1 * 3 + 0] - qx;
        const float dy = s_points[idx1 * 3 + 1] - qy;
        const float dz = s_points[idx1 * 3 + 2] - qz;
        float wbuf[8];
#pragma unroll
        for (int j = 0; j < 8; ++j) {
            const int k = khalf * 8 + j;
            float w = 0.f;
            if (k < K_PTS) {
                const float ex = dx - kpx[k];
                const float ey = dy - kpy[k];
                const float ez = dz - kpz[k];
                const float sq = ex * ex + ey * ey + ez * ez;
                w = 1.f - sqrtf(sq) * (1.f / SIGMA_);
                w = w > 0.f ? w : 0.f;
            }
            wbuf[j] = w;
        }
        {   // two aligned float4 stores into this wave's slab
            float4 wa = make_float4(wbuf[0], wbuf[1], wbuf[2], wbuf[3]);
            float4 wb = make_float4(wbuf[4], wbuf[5], wbuf[6], wbuf[7]);
            *(float4*)&w_lds[wid][h1][khalf * 8 + 0] = wa;
            *(float4*)&w_lds[wid][h1][khalf * 8 + 4] = wb;
        }
        // intra-wave LDS RAW: DS unit processes a wave's LDS ops in order;
        // compiler inserts lgkmcnt for the dependent reads below.

        // ---------------- phase 2: weighted[k][c], lane = channel --------
        float acc[K_PTS];
#pragma unroll
        for (int k = 0; k < K_PTS; ++k) acc[k] = 0.f;
        int cnt = 0;
        for (int h = 0; h < H_NB; ++h) {
            const int sidx = nbr_idx[m * H_NB + h];       // uniform -> s_load
            const float f = s_feats[sidx * CIN + lane];   // coalesced 256B
            // validity: sum over all 64 channels > 0
            float r = f;
#pragma unroll
            for (int msk = 1; msk < 64; msk <<= 1) r += __shfl_xor(r, msk, 64);
            cnt += (r > 0.f) ? 1 : 0;
            const float4 w0 = *(const float4*)&w_lds[wid][h][0];
            const float4 w1 = *(const float4*)&w_lds[wid][h][4];
            const float4 w2 = *(const float4*)&w_lds[wid][h][8];
            const float4 w3 = *(const float4*)&w_lds[wid][h][12];
            acc[0]  += w0.x * f;  acc[1]  += w0.y * f;
            acc[2]  += w0.z * f;  acc[3]  += w0.w * f;
            acc[4]  += w1.x * f;  acc[5]  += w1.y * f;
            acc[6]  += w1.z * f;  acc[7]  += w1.w * f;
            acc[8]  += w2.x * f;  acc[9]  += w2.y * f;
            acc[10] += w2.z * f;  acc[11] += w2.w * f;
            acc[12] += w3.x * f;  acc[13] += w3.y * f;
            acc[14] += w3.z * f;
        }
#pragma unroll
        for (int k = 0; k < K_PTS; ++k)
            wtd_lds[q][k][lane] = f_to_bf16(acc[k]);
        if (lane == 0) nbr_lds[q] = (float)(cnt > 0 ? cnt : 1);
    }
    __syncthreads();

    // ---------------- phase 3: out[m,d] = sum_{k,c} wtd * W[k,c,d] -------
    // wave `wid` handles kernel points [wid*4, wid*4+kcnt)
    {
        const int kstart = wid * 4;
        const int kcnt = (wid == 3) ? 3 : 4;
        float outp[QPB];
#pragma unroll
        for (int q = 0; q < QPB; ++q) outp[q] = 0.f;
        for (int kk = 0; kk < kcnt; ++kk) {
            const int k = kstart + kk;
            for (int c4 = 0; c4 < CIN / 4; ++c4) {
                const int c = c4 * 4;
                const float wv0 = weights[((k * CIN) + c + 0) * COUT + lane];
                const float wv1 = weights[((k * CIN) + c + 1) * COUT + lane];
                const float wv2 = weights[((k * CIN) + c + 2) * COUT + lane];
                const float wv3 = weights[((k * CIN) + c + 3) * COUT + lane];
#pragma unroll
            for (int q = 0; q < QPB; ++q) {
                    const uint2 u = *(const uint2*)&wtd_lds[q][k][c];
                    const float f0 = __builtin_bit_cast(float, u.x << 16);
                    const float f1 = __builtin_bit_cast(float, u.x & 0xffff0000u);
                    const float f2 = __builtin_bit_cast(float, u.y << 16);
                    const float f3 = __builtin_bit_cast(float, u.y & 0xffff0000u);
                    outp[q] += f0 * wv0 + f1 * wv1 + f2 * wv2 + f3 * wv3;
                }
            }
        }
#pragma unroll
        for (int q = 0; q < QPB; ++q) atomicAdd(&y_red[q][lane], outp[q]);
    }
    __syncthreads();

    // ---------------- phase 4: normalize, bias, store, group stats -------
    {
        const int d = tid & 63;
        const float bv = bias[d];
        float s1 = 0.f, s2 = 0.f;
#pragma unroll
        for (int j = 0; j < (QPB * COUT) / 256; ++j) {   // 4
            const int pid = tid + 256 * j;
            const int q = pid >> 6;
            const float yv = y_red[q][d] / nbr_lds[q] + bv;
            y_out[(blockIdx.x * QPB + q) * COUT + d] = yv;
            s1 += yv;
            s2 += yv * yv;
        }
        // reduce across the 8 lanes sharing a channel-group
        s1 += __shfl_xor(s1, 1, 64);  s2 += __shfl_xor(s2, 1, 64);
        s1 += __shfl_xor(s1, 2, 64);  s2 += __shfl_xor(s2, 2, 64);
        s1 += __shfl_xor(s1, 4, 64);  s2 += __shfl_xor(s2, 4, 64);
        if ((lane & 7) == 0) {
            const int g = d >> 3;
            atomicAdd(&gstats[g], s1);
            atomicAdd(&gstats[8 + g], s2);
        }
    }
}

__global__ __launch_bounds__(256) void gn_kernel(
    const float* __restrict__ gstats,
    const float* __restrict__ gamma,
    const float* __restrict__ beta,
    float* __restrict__ out)   // in-place on d_out
{
    const int idx4 = blockIdx.x * blockDim.x + threadIdx.x;  // float4 index
    const int d4 = idx4 & (COUT / 4 - 1);   // float4 slot within a row
    const int d = d4 * 4;
    const int g = d >> 3;                   // float4 never crosses a group
    const float cntinv = 1.f / (float)(M_Q * (COUT / NGROUPS));
    const float mean = gstats[g] * cntinv;
    const float var = gstats[8 + g] * cntinv - mean * mean;
    const float rs = rsqrtf(var + GEPS);
    float4 y = ((const float4*)out)[idx4];
    const float4 gm = ((const float4*)gamma)[d4];
    const float4 bt = ((const float4*)beta)[d4];
    float v;
    v = (y.x - mean) * rs * gm.x + bt.x;  y.x = v >= 0.f ? v : NEG_SLOPE_ * v;
    v = (y.y - mean) * rs * gm.y + bt.y;  y.y = v >= 0.f ? v : NEG_SLOPE_ * v;
    v = (y.z - mean) * rs * gm.z + bt.z;  y.z = v >= 0.f ? v : NEG_SLOPE_ * v;
    v = (y.w - mean) * rs * gm.w + bt.w;  y.w = v >= 0.f ? v : NEG_SLOPE_ * v;
    ((float4*)out)[idx4] = y;
}

extern "C" void kernel_launch(void* const* d_in, const int* in_sizes, int n_in,
                              void* d_out, int out_size, void* d_ws, size_t ws_size,
                              hipStream_t stream) {
    const float* s_feats  = (const float*)d_in[0];
    const float* q_points = (const float*)d_in[1];
    const float* s_points = (const float*)d_in[2];
    const int*   nbr      = (const int*)d_in[3];
    const float* kpts     = (const float*)d_in[4];
    const float* weights  = (const float*)d_in[5];
    const float* bias     = (const float*)d_in[6];
    const float* gamma    = (const float*)d_in[7];
    const float* beta     = (const float*)d_in[8];
    float* out   = (float*)d_out;
    float* stats = (float*)d_ws;   // 16 floats

    hipMemsetAsync(stats, 0, 16 * sizeof(float), stream);
    kpconv_kernel<<<M_Q / QPB, 256, 0, stream>>>(
        s_feats, q_points, s_points, nbr, kpts, weights, bias, out, stats);
    gn_kernel<<<(M_Q * COUT / 4) / 256, 256, 0, stream>>>(stats, gamma, beta, out);
}

// Round 2
// 265.430 us; speedup vs baseline: 1.3177x; 1.3177x over previous
//
#include <hip/hip_runtime.h>
#include <hip/hip_bf16.h>

#define N_SUP 32768
#define M_Q 32768
#define H_NB 32
#define K_PTS 15
#define CIN 64
#define COUT 64
#define SIGMA_ 0.1f
#define NGROUPS 8
#define NEG_SLOPE_ 0.1f
#define GEPS 1e-5f

#define QPB 16   // queries per block
#define NWAVES 4
#define KSTEPS 30  // 960 / 32

typedef __attribute__((ext_vector_type(8))) short bf16x8;
typedef __attribute__((ext_vector_type(4))) float f32x4;

__device__ __forceinline__ unsigned short f_to_bf16(float f) {
    unsigned int x = __builtin_bit_cast(unsigned int, f);
    unsigned int r = (x + 0x7fffu + ((x >> 16) & 1u)) >> 16;
    return (unsigned short)r;
}

// ---- prep 1: per-support-row validity (sum over channels > 0) ----
__global__ __launch_bounds__(256) void prep_valid_kernel(
    const float* __restrict__ s_feats, float* __restrict__ valid)
{
    const int row  = blockIdx.x * 4 + (threadIdx.x >> 6);
    const int lane = threadIdx.x & 63;
    float f = s_feats[row * CIN + lane];
#pragma unroll
    for (int m = 1; m < 64; m <<= 1) f += __shfl_xor(f, m, 64);
    if (lane == 0) valid[row] = (f > 0.f) ? 1.f : 0.f;
}

// ---- prep 2: pack conv weights [960][64] f32 -> bf16 B-fragments ----
// wpack[wt][s][lane][j] = W[s*32 + (lane>>4)*8 + j][wt*16 + (lane&15)]
__global__ __launch_bounds__(256) void prep_wpack_kernel(
    const float* __restrict__ weights, unsigned short* __restrict__ wpack)
{
    const int t = blockIdx.x * 256 + threadIdx.x;
    if (t >= NWAVES * KSTEPS * 64) return;
    const int l  = t & 63;
    const int s  = (t >> 6) % KSTEPS;
    const int wt = t / (KSTEPS * 64);
    const int kp = s * 32 + ((l >> 4) << 3);
    const int d  = wt * 16 + (l & 15);
    unsigned short v[8];
#pragma unroll
    for (int j = 0; j < 8; ++j)
        v[j] = f_to_bf16(weights[(kp + j) * COUT + d]);
    uint4 u;
    u.x = (unsigned)v[0] | ((unsigned)v[1] << 16);
    u.y = (unsigned)v[2] | ((unsigned)v[3] << 16);
    u.z = (unsigned)v[4] | ((unsigned)v[5] << 16);
    u.w = (unsigned)v[6] | ((unsigned)v[7] << 16);
    *(uint4*)&wpack[t * 8] = u;
}

__global__ __launch_bounds__(256) void kpconv_kernel(
    const float* __restrict__ s_feats,
    const float* __restrict__ q_points,
    const float* __restrict__ s_points,
    const int*   __restrict__ nbr_idx,
    const float* __restrict__ kpts,
    const unsigned short* __restrict__ wpack,
    const float* __restrict__ valid,
    const float* __restrict__ bias,
    float* __restrict__ y_out,      // d_out: pre-GN conv output [M, COUT]
    float* __restrict__ gstats)     // ws: 16 floats (sum[8], sumsq[8])
{
    __shared__ float w_lds[NWAVES][H_NB][16];            // 8 KB
    // bf16 weighted features; within each (q,k) row of 64 ch, 16B chunks are
    // XOR-swizzled by (q&7) so phase-3 ds_read_b128 across q-rows is conflict-free
    __shared__ unsigned short wtd_lds[QPB][K_PTS][CIN];  // 30 KB
    __shared__ float nbr_lds[QPB];                       // reciprocal of count

    const int tid  = threadIdx.x;
    const int lane = tid & 63;
    const int wid  = __builtin_amdgcn_readfirstlane(tid >> 6);

    // kernel points (uniform -> scalar regs)
    float kpx[K_PTS], kpy[K_PTS], kpz[K_PTS];
#pragma unroll
    for (int k = 0; k < K_PTS; ++k) {
        kpx[k] = kpts[k * 3 + 0];
        kpy[k] = kpts[k * 3 + 1];
        kpz[k] = kpts[k * 3 + 2];
    }

    const int h1    = lane >> 1;   // phase-1: 2 lanes per neighbor
    const int khalf = lane & 1;    // each lane does 8 kernel points

    for (int i = 0; i < QPB / NWAVES; ++i) {
        const int q = wid * (QPB / NWAVES) + i;
        const int m = blockIdx.x * QPB + q;

        // ---------------- phase 1: w[h][k], lane-parallel ----------------
        const float qx = q_points[m * 3 + 0];
        const float qy = q_points[m * 3 + 1];
        const float qz = q_points[m * 3 + 2];
        const int idx1 = nbr_idx[m * H_NB + h1];
        const float dx = s_points[idx1 * 3 + 0] - qx;
        const float dy = s_points[idx1 * 3 + 1] - qy;
        const float dz = s_points[idx1 * 3 + 2] - qz;
        float wbuf[8];
#pragma unroll
        for (int j = 0; j < 8; ++j) {
            const int k = khalf * 8 + j;
            float w = 0.f;
            if (k < K_PTS) {
                const float ex = dx - kpx[k];
                const float ey = dy - kpy[k];
                const float ez = dz - kpz[k];
                const float sq = ex * ex + ey * ey + ez * ez;
                w = 1.f - sqrtf(sq) * (1.f / SIGMA_);
                w = w > 0.f ? w : 0.f;
            }
            wbuf[j] = w;
        }
        {
            float4 wa = make_float4(wbuf[0], wbuf[1], wbuf[2], wbuf[3]);
            float4 wb = make_float4(wbuf[4], wbuf[5], wbuf[6], wbuf[7]);
            *(float4*)&w_lds[wid][h1][khalf * 8 + 0] = wa;
            *(float4*)&w_lds[wid][h1][khalf * 8 + 4] = wb;
        }
        // intra-wave LDS RAW ordering handled by compiler lgkmcnt

        // ---------------- phase 2: weighted[k][c], lane = channel --------
        float acc[K_PTS];
#pragma unroll
        for (int k = 0; k < K_PTS; ++k) acc[k] = 0.f;
        float cntf = 0.f;
#pragma unroll 2
        for (int h = 0; h < H_NB; ++h) {
            const int sidx = nbr_idx[m * H_NB + h];       // uniform -> s_load
            const float f = s_feats[sidx * CIN + lane];   // coalesced 256B
            cntf += valid[sidx];                          // uniform -> s_load
            const float4 w0 = *(const float4*)&w_lds[wid][h][0];
            const float4 w1 = *(const float4*)&w_lds[wid][h][4];
            const float4 w2 = *(const float4*)&w_lds[wid][h][8];
            const float4 w3 = *(const float4*)&w_lds[wid][h][12];
            acc[0]  += w0.x * f;  acc[1]  += w0.y * f;
            acc[2]  += w0.z * f;  acc[3]  += w0.w * f;
            acc[4]  += w1.x * f;  acc[5]  += w1.y * f;
            acc[6]  += w1.z * f;  acc[7]  += w1.w * f;
            acc[8]  += w2.x * f;  acc[9]  += w2.y * f;
            acc[10] += w2.z * f;  acc[11] += w2.w * f;
            acc[12] += w3.x * f;  acc[13] += w3.y * f;
            acc[14] += w3.z * f;
        }
        // swizzled store: chunk' = (c>>3) ^ (q&7), keep low 3 bits of c
        const int cswz = (((lane >> 3) ^ (q & 7)) << 3) | (lane & 7);
#pragma unroll
        for (int k = 0; k < K_PTS; ++k)
            wtd_lds[q][k][cswz] = f_to_bf16(acc[k]);
        if (lane == 0) nbr_lds[q] = 1.f / (cntf > 1.f ? cntf : 1.f);
    }
    __syncthreads();

    // ------- phase 3: MFMA GEMM  out[16q x 64d] = wtd[16q x 960] * W -------
    // wave `wid` owns d-columns [wid*16, wid*16+16)
    {
        f32x4 acc3 = {0.f, 0.f, 0.f, 0.f};
        const int qa  = lane & 15;          // A-row (query)
        const int grp = lane >> 4;          // k-subblock
        const unsigned short* wp = &wpack[(wid * KSTEPS) * 64 * 8 + lane * 8];
        for (int s = 0; s < KSTEPS; ++s) {
            const int k  = s >> 1;
            const int ch = (((s & 1) * 4 + grp) ^ (lane & 7));  // swizzled chunk
            bf16x8 a = *(const bf16x8*)&wtd_lds[qa][k][ch * 8];
            bf16x8 b = *(const bf16x8*)&wp[s * 512];
            acc3 = __builtin_amdgcn_mfma_f32_16x16x32_bf16(a, b, acc3, 0, 0, 0);
        }
        // epilogue: C layout col=lane&15, row=(lane>>4)*4+r
        const int dl = wid * 16 + (lane & 15);
        const float bv = bias[dl];
        float s1 = 0.f, s2 = 0.f;
#pragma unroll
        for (int r = 0; r < 4; ++r) {
            const int qq = grp * 4 + r;
            const float yv = acc3[r] * nbr_lds[qq] + bv;
            y_out[(blockIdx.x * QPB + qq) * COUT + dl] = yv;
            s1 += yv;
            s2 += yv * yv;
        }
        // reduce over lanes sharing group g (all bits except lane bit 3)
        s1 += __shfl_xor(s1, 1, 64);   s2 += __shfl_xor(s2, 1, 64);
        s1 += __shfl_xor(s1, 2, 64);   s2 += __shfl_xor(s2, 2, 64);
        s1 += __shfl_xor(s1, 4, 64);   s2 += __shfl_xor(s2, 4, 64);
        s1 += __shfl_xor(s1, 16, 64);  s2 += __shfl_xor(s2, 16, 64);
        s1 += __shfl_xor(s1, 32, 64);  s2 += __shfl_xor(s2, 32, 64);
        if (lane == 0 || lane == 8) {
            const int g = wid * 2 + ((lane >> 3) & 1);
            atomicAdd(&gstats[g], s1);
            atomicAdd(&gstats[8 + g], s2);
        }
    }
}

__global__ __launch_bounds__(256) void gn_kernel(
    const float* __restrict__ gstats,
    const float* __restrict__ gamma,
    const float* __restrict__ beta,
    float* __restrict__ out)   // in-place on d_out
{
    const int idx4 = blockIdx.x * blockDim.x + threadIdx.x;  // float4 index
    const int d4 = idx4 & (COUT / 4 - 1);
    const int d = d4 * 4;
    const int g = d >> 3;
    const float cntinv = 1.f / (float)(M_Q * (COUT / NGROUPS));
    const float mean = gstats[g] * cntinv;
    const float var = gstats[8 + g] * cntinv - mean * mean;
    const float rs = rsqrtf(var + GEPS);
    float4 y = ((const float4*)out)[idx4];
    const float4 gm = ((const float4*)gamma)[d4];
    const float4 bt = ((const float4*)beta)[d4];
    float v;
    v = (y.x - mean) * rs * gm.x + bt.x;  y.x = v >= 0.f ? v : NEG_SLOPE_ * v;
    v = (y.y - mean) * rs * gm.y + bt.y;  y.y = v >= 0.f ? v : NEG_SLOPE_ * v;
    v = (y.z - mean) * rs * gm.z + bt.z;  y.z = v >= 0.f ? v : NEG_SLOPE_ * v;
    v = (y.w - mean) * rs * gm.w + bt.w;  y.w = v >= 0.f ? v : NEG_SLOPE_ * v;
    ((float4*)out)[idx4] = y;
}

extern "C" void kernel_launch(void* const* d_in, const int* in_sizes, int n_in,
                              void* d_out, int out_size, void* d_ws, size_t ws_size,
                              hipStream_t stream) {
    const float* s_feats  = (const float*)d_in[0];
    const float* q_points = (const float*)d_in[1];
    const float* s_points = (const float*)d_in[2];
    const int*   nbr      = (const int*)d_in[3];
    const float* kpts     = (const float*)d_in[4];
    const float* weights  = (const float*)d_in[5];
    const float* bias     = (const float*)d_in[6];
    const float* gamma    = (const float*)d_in[7];
    const float* beta     = (const float*)d_in[8];
    float* out = (float*)d_out;

    // ws layout: [0:16) stats | [16:16+32768) valid | then wpack (bf16)
    float* stats = (float*)d_ws;
    float* valid = stats + 16;
    unsigned short* wpack = (unsigned short*)(valid + N_SUP);  // 61440 ushort

    hipMemsetAsync(stats, 0, 16 * sizeof(float), stream);
    prep_valid_kernel<<<N_SUP / 4, 256, 0, stream>>>(s_feats, valid);
    prep_wpack_kernel<<<(NWAVES * KSTEPS * 64 + 255) / 256, 256, 0, stream>>>(weights, wpack);
    kpconv_kernel<<<M_Q / QPB, 256, 0, stream>>>(
        s_feats, q_points, s_points, nbr, kpts, wpack, valid, bias, out, stats);
    gn_kernel<<<(M_Q * COUT / 4) / 256, 256, 0, stream>>>(stats, gamma, beta, out);
}

// Round 3
// 255.603 us; speedup vs baseline: 1.3684x; 1.0384x over previous
//
#include <hip/hip_runtime.h>
#include <hip/hip_bf16.h>

#define N_SUP 32768
#define M_Q 32768
#define H_NB 32
#define K_PTS 15
#define CIN 64
#define COUT 64
#define SIGMA_ 0.1f
#define NGROUPS 8
#define NEG_SLOPE_ 0.1f
#define GEPS 1e-5f

#define QPB 16   // queries per block
#define NWAVES 4
#define KSTEPS 30  // 960 / 32

typedef __attribute__((ext_vector_type(8))) short bf16x8;
typedef __attribute__((ext_vector_type(4))) float f32x4;
typedef __attribute__((ext_vector_type(2))) float f32x2;

__device__ __forceinline__ unsigned short f_to_bf16(float f) {
    unsigned int x = __builtin_bit_cast(unsigned int, f);
    unsigned int r = (x + 0x7fffu + ((x >> 16) & 1u)) >> 16;
    return (unsigned short)r;
}

// ---- prep 1: per-support-row validity (sum over channels > 0) ----
__global__ __launch_bounds__(256) void prep_valid_kernel(
    const float* __restrict__ s_feats, float* __restrict__ valid)
{
    const int row  = blockIdx.x * 4 + (threadIdx.x >> 6);
    const int lane = threadIdx.x & 63;
    float f = s_feats[row * CIN + lane];
#pragma unroll
    for (int m = 1; m < 64; m <<= 1) f += __shfl_xor(f, m, 64);
    if (lane == 0) valid[row] = (f > 0.f) ? 1.f : 0.f;
}

// ---- prep 1b: per-query reciprocal neighbor count ----
__global__ __launch_bounds__(256) void prep_cnt_kernel(
    const int* __restrict__ nbr, const float* __restrict__ valid,
    float* __restrict__ rcnt)
{
    const int w = threadIdx.x >> 6, lane = threadIdx.x & 63;
    const int m = blockIdx.x * 8 + w * 2 + (lane >> 5);
    const int h = lane & 31;
    float v = valid[nbr[m * H_NB + h]];
#pragma unroll
    for (int msk = 1; msk < 32; msk <<= 1) v += __shfl_xor(v, msk, 64);
    if (h == 0) rcnt[m] = 1.f / fmaxf(v, 1.f);
}

// ---- prep 2: pack conv weights [960][64] f32 -> bf16 B-fragments ----
__global__ __launch_bounds__(256) void prep_wpack_kernel(
    const float* __restrict__ weights, unsigned short* __restrict__ wpack)
{
    const int t = blockIdx.x * 256 + threadIdx.x;
    if (t >= NWAVES * KSTEPS * 64) return;
    const int l  = t & 63;
    const int s  = (t >> 6) % KSTEPS;
    const int wt = t / (KSTEPS * 64);
    const int kp = s * 32 + ((l >> 4) << 3);
    const int d  = wt * 16 + (l & 15);
    unsigned short v[8];
#pragma unroll
    for (int j = 0; j < 8; ++j)
        v[j] = f_to_bf16(weights[(kp + j) * COUT + d]);
    uint4 u;
    u.x = (unsigned)v[0] | ((unsigned)v[1] << 16);
    u.y = (unsigned)v[2] | ((unsigned)v[3] << 16);
    u.z = (unsigned)v[4] | ((unsigned)v[5] << 16);
    u.w = (unsigned)v[6] | ((unsigned)v[7] << 16);
    *(uint4*)&wpack[t * 8] = u;
}

__global__ __launch_bounds__(256) void kpconv_kernel(
    const float* __restrict__ s_feats,
    const float* __restrict__ q_points,
    const float* __restrict__ s_points,
    const int*   __restrict__ nbr_idx,
    const float* __restrict__ kpts,
    const unsigned short* __restrict__ wpack,
    const float* __restrict__ rcnt,
    const float* __restrict__ bias,
    float* __restrict__ y_out,      // d_out: pre-GN conv output [M, COUT]
    float* __restrict__ gstats)     // ws: 16 floats (sum[8], sumsq[8])
{
    __shared__ float w_lds[NWAVES][2][H_NB][16];         // 16 KB (ping-pong)
    __shared__ unsigned short wtd_lds[QPB][K_PTS][CIN];  // 30 KB (bf16, q-swizzled)
    __shared__ float nbr_lds[QPB];

    const int tid  = threadIdx.x;
    const int lane = tid & 63;
    const int wid  = __builtin_amdgcn_readfirstlane(tid >> 6);

    // kernel points (uniform -> scalar regs)
    float kpx[K_PTS], kpy[K_PTS], kpz[K_PTS];
#pragma unroll
    for (int k = 0; k < K_PTS; ++k) {
        kpx[k] = kpts[k * 3 + 0];
        kpy[k] = kpts[k * 3 + 1];
        kpz[k] = kpts[k * 3 + 2];
    }

    const int h1    = lane >> 1;   // phase-1: 2 lanes per neighbor
    const int khalf = lane & 1;
    const int half  = lane >> 5;   // phase-2: 0 = even h rows, 1 = odd h rows
    const int cpair = lane & 31;   // phase-2: channels {2*cpair, 2*cpair+1}

    f32x2 fA[16], fB[16];

    auto phase1 = [&](int i, int slot) {
        const int m = blockIdx.x * QPB + wid * 4 + i;
        const float qx = q_points[m * 3 + 0];
        const float qy = q_points[m * 3 + 1];
        const float qz = q_points[m * 3 + 2];
        const int idx1 = nbr_idx[m * H_NB + h1];
        const float dx = s_points[idx1 * 3 + 0] - qx;
        const float dy = s_points[idx1 * 3 + 1] - qy;
        const float dz = s_points[idx1 * 3 + 2] - qz;
        float wb[8];
#pragma unroll
        for (int j = 0; j < 8; ++j) {
            const int k = khalf * 8 + j;
            float w = 0.f;
            if (k < K_PTS) {
                const float ex = dx - kpx[k];
                const float ey = dy - kpy[k];
                const float ez = dz - kpz[k];
                w = fmaxf(1.f - sqrtf(ex * ex + ey * ey + ez * ez) * (1.f / SIGMA_), 0.f);
            }
            wb[j] = w;
        }
        *(float4*)&w_lds[wid][slot][h1][khalf * 8 + 0] = make_float4(wb[0], wb[1], wb[2], wb[3]);
        *(float4*)&w_lds[wid][slot][h1][khalf * 8 + 4] = make_float4(wb[4], wb[5], wb[6], wb[7]);
        if (lane == 0) nbr_lds[wid * 4 + i] = rcnt[m];
    };

    auto issue = [&](int i, f32x2 (&fb)[16]) {
        const int m = blockIdx.x * QPB + wid * 4 + i;
#pragma unroll
        for (int t = 0; t < 16; ++t) {
            const int i0 = nbr_idx[m * H_NB + 2 * t + 0];   // uniform -> s_load
            const int i1 = nbr_idx[m * H_NB + 2 * t + 1];
            const int sidx = half ? i1 : i0;                // cndmask, per-lane
            fb[t] = *(const f32x2*)&s_feats[sidx * CIN + cpair * 2];
        }
    };

    auto consume = [&](int i, int slot, f32x2 (&fb)[16]) {
        const int q = wid * 4 + i;
        f32x2 acc[K_PTS];
#pragma unroll
        for (int k = 0; k < K_PTS; ++k) acc[k] = (f32x2){0.f, 0.f};
#pragma unroll
        for (int t = 0; t < 16; ++t) {
            const int hh = 2 * t + half;
            const float4 w0 = *(const float4*)&w_lds[wid][slot][hh][0];
            const float4 w1 = *(const float4*)&w_lds[wid][slot][hh][4];
            const float4 w2 = *(const float4*)&w_lds[wid][slot][hh][8];
            const float4 w3 = *(const float4*)&w_lds[wid][slot][hh][12];
            const f32x2 fv = fb[t];
            acc[0]  += fv * w0.x;  acc[1]  += fv * w0.y;
            acc[2]  += fv * w0.z;  acc[3]  += fv * w0.w;
            acc[4]  += fv * w1.x;  acc[5]  += fv * w1.y;
            acc[6]  += fv * w1.z;  acc[7]  += fv * w1.w;
            acc[8]  += fv * w2.x;  acc[9]  += fv * w2.y;
            acc[10] += fv * w2.z;  acc[11] += fv * w2.w;
            acc[12] += fv * w3.x;  acc[13] += fv * w3.y;
            acc[14] += fv * w3.z;
        }
        // combine even-h / odd-h halves
#pragma unroll
        for (int k = 0; k < K_PTS; ++k) {
            acc[k].x += __shfl_xor(acc[k].x, 32, 64);
            acc[k].y += __shfl_xor(acc[k].y, 32, 64);
        }
        // bf16 pack + swizzled store; half0 stores k=0..7, half1 k=8..14
        const int cbase = cpair * 2;
        const int c0 = (((cbase >> 3) ^ (q & 7)) << 3) | (cbase & 7);
#pragma unroll
        for (int k = 0; k < K_PTS; ++k) {
            if ((k >> 3) == half) {
                unsigned int u;
                asm("v_cvt_pk_bf16_f32 %0, %1, %2"
                    : "=v"(u) : "v"(acc[k].x), "v"(acc[k].y));
                *(unsigned int*)&wtd_lds[q][k][c0] = u;
            }
        }
    };

    // software pipeline: phase1/issue for q+1 overlap consume of q
    phase1(0, 0);
    issue(0, fA);
    phase1(1, 1);  issue(1, fB);  consume(0, 0, fA);
    phase1(2, 0);  issue(2, fA);  consume(1, 1, fB);
    phase1(3, 1);  issue(3, fB);  consume(2, 0, fA);
    consume(3, 1, fB);
    __syncthreads();

    // ------- phase 3: MFMA GEMM  out[16q x 64d] = wtd[16q x 960] * W -------
    {
        f32x4 acc3 = {0.f, 0.f, 0.f, 0.f};
        const int qa  = lane & 15;
        const int grp = lane >> 4;
        const unsigned short* wp = &wpack[(wid * KSTEPS) * 64 * 8 + lane * 8];
        for (int s = 0; s < KSTEPS; ++s) {
            const int k  = s >> 1;
            const int ch = (((s & 1) * 4 + grp) ^ (lane & 7));  // q-row swizzle
            bf16x8 a = *(const bf16x8*)&wtd_lds[qa][k][ch * 8];
            bf16x8 b = *(const bf16x8*)&wp[s * 512];
            acc3 = __builtin_amdgcn_mfma_f32_16x16x32_bf16(a, b, acc3, 0, 0, 0);
        }
        // epilogue: C layout col=lane&15 (query? no: col=q), row=(lane>>4)*4+r
        const int dl = wid * 16 + (lane & 15);
        const float bv = bias[dl];
        float s1 = 0.f, s2 = 0.f;
#pragma unroll
        for (int r = 0; r < 4; ++r) {
            const int qq = grp * 4 + r;
            const float yv = acc3[r] * nbr_lds[qq] + bv;
            y_out[(blockIdx.x * QPB + qq) * COUT + dl] = yv;
            s1 += yv;
            s2 += yv * yv;
        }
        s1 += __shfl_xor(s1, 1, 64);   s2 += __shfl_xor(s2, 1, 64);
        s1 += __shfl_xor(s1, 2, 64);   s2 += __shfl_xor(s2, 2, 64);
        s1 += __shfl_xor(s1, 4, 64);   s2 += __shfl_xor(s2, 4, 64);
        s1 += __shfl_xor(s1, 16, 64);  s2 += __shfl_xor(s2, 16, 64);
        s1 += __shfl_xor(s1, 32, 64);  s2 += __shfl_xor(s2, 32, 64);
        if (lane == 0 || lane == 8) {
            const int g = wid * 2 + ((lane >> 3) & 1);
            atomicAdd(&gstats[g], s1);
            atomicAdd(&gstats[8 + g], s2);
        }
    }
}

__global__ __launch_bounds__(256) void gn_kernel(
    const float* __restrict__ gstats,
    const float* __restrict__ gamma,
    const float* __restrict__ beta,
    float* __restrict__ out)   // in-place on d_out
{
    const int idx4 = blockIdx.x * blockDim.x + threadIdx.x;
    const int d4 = idx4 & (COUT / 4 - 1);
    const int d = d4 * 4;
    const int g = d >> 3;
    const float cntinv = 1.f / (float)(M_Q * (COUT / NGROUPS));
    const float mean = gstats[g] * cntinv;
    const float var = gstats[8 + g] * cntinv - mean * mean;
    const float rs = rsqrtf(var + GEPS);
    float4 y = ((const float4*)out)[idx4];
    const float4 gm = ((const float4*)gamma)[d4];
    const float4 bt = ((const float4*)beta)[d4];
    float v;
    v = (y.x - mean) * rs * gm.x + bt.x;  y.x = v >= 0.f ? v : NEG_SLOPE_ * v;
    v = (y.y - mean) * rs * gm.y + bt.y;  y.y = v >= 0.f ? v : NEG_SLOPE_ * v;
    v = (y.z - mean) * rs * gm.z + bt.z;  y.z = v >= 0.f ? v : NEG_SLOPE_ * v;
    v = (y.w - mean) * rs * gm.w + bt.w;  y.w = v >= 0.f ? v : NEG_SLOPE_ * v;
    ((float4*)out)[idx4] = y;
}

extern "C" void kernel_launch(void* const* d_in, const int* in_sizes, int n_in,
                              void* d_out, int out_size, void* d_ws, size_t ws_size,
                              hipStream_t stream) {
    const float* s_feats  = (const float*)d_in[0];
    const float* q_points = (const float*)d_in[1];
    const float* s_points = (const float*)d_in[2];
    const int*   nbr      = (const int*)d_in[3];
    const float* kpts     = (const float*)d_in[4];
    const float* weights  = (const float*)d_in[5];
    const float* bias     = (const float*)d_in[6];
    const float* gamma    = (const float*)d_in[7];
    const float* beta     = (const float*)d_in[8];
    float* out = (float*)d_out;

    // ws layout: stats[16] | valid[N] | rcnt[M] | wpack (bf16)
    float* stats = (float*)d_ws;
    float* valid = stats + 16;
    float* rcnt  = valid + N_SUP;
    unsigned short* wpack = (unsigned short*)(rcnt + M_Q);  // 61440 ushort

    hipMemsetAsync(stats, 0, 16 * sizeof(float), stream);
    prep_valid_kernel<<<N_SUP / 4, 256, 0, stream>>>(s_feats, valid);
    prep_cnt_kernel<<<M_Q / 8, 256, 0, stream>>>(nbr, valid, rcnt);
    prep_wpack_kernel<<<(NWAVES * KSTEPS * 64 + 255) / 256, 256, 0, stream>>>(weights, wpack);
    kpconv_kernel<<<M_Q / QPB, 256, 0, stream>>>(
        s_feats, q_points, s_points, nbr, kpts, wpack, rcnt, bias, out, stats);
    gn_kernel<<<(M_Q * COUT / 4) / 256, 256, 0, stream>>>(stats, gamma, beta, out);
}